// Round 8
// baseline (127.639 us; speedup 1.0000x reference)
//
#include <hip/hip_runtime.h>

// INRF fused:  out[b,ij,c] = sum_pq [ M2[ij,pq]*x[b,pq,c] - W2[ij,pq]*relu(x[b,pq,c] - S[b,pq,ij,c]) ]
//   S[b,pq,ij,f] = sum_k patch(x)[b,pq,k] * G[ij,k,f]   (3x3 SAME conv, K=144->pad 160)
//
// Round-8: all structures pin at 42-56us; per-SIMD accounting shows in-loop VALU
//   (~290 instr/iter, 37K cyc/SIMD) is the largest busy pipe and sits serially in the
//   dependence chain. This round = R1 (best, 42-47us) with the VALU cut ~4x:
//   (1) M2*x hoisted OUT of the loop: F = M2@x computed fp32-exact in build_pre;
//       inrf accumulates only sum(W2*relu(x-S)); out = F - sum. No new rounding.
//   (2) packed-f32 epilogue: float4 vector ops -> v_pk_{add,max,fma}_f32, vector accs.
//   (3) B-frags from pre-packed Gf (20 coalesced dwordx4) not 160 scalar gathers.
//   Structure otherwise identical to R1: 256 blocks x 512 thr, 4 ij/block, register
//   ping-pong A/x prefetch, direct store, no atomics, no out-zero.

typedef __attribute__((ext_vector_type(8))) short bf16x8;
typedef __attribute__((ext_vector_type(4))) float f32x4;

__device__ inline unsigned short f2bf(float x) {
    unsigned u = __float_as_uint(x);
    u += 0x7FFFu + ((u >> 16) & 1u);          // round-to-nearest-even
    return (unsigned short)(u >> 16);
}
__device__ inline unsigned pack2(float a, float b) {
    return (unsigned)f2bf(a) | ((unsigned)f2bf(b) << 16);
}

// ---------------- Phase 1: A (im2col bf16 frags) + Xf + Gf + F = M2@x ----------------
// unit u = tid>>12:
//   u in [0,18):   A tap = u>>1, h = u&1 -> uint4 at (tile, kk=tap>>1, quad=(tap&1)*2+h, m)
//   u in [18,20):  A zero-pad kk=4, quads 2,3
//   u in [20,24):  Xf C-frag gather, one float4 per (tile, lane)
//   u in [24,104): Gf pack: one uint4 per (ij, kk, lane)
//   u in [104,120): F[b,ij,c] = sum_pq M2[ij,pq]*x[b,pq,c]  (fp32, one thread/output)
__global__ __launch_bounds__(256) void build_pre(const float* __restrict__ inp,
                                                 const float* __restrict__ Mm,
                                                 const float* __restrict__ G,
                                                 uint4* __restrict__ A,
                                                 float4* __restrict__ Xf,
                                                 uint4* __restrict__ Gf,
                                                 float* __restrict__ F) {
    const int tid = blockIdx.x * 256 + threadIdx.x;
    const int u = tid >> 12;
    if (u >= 104) {                           // F: 65536 outputs, wave-uniform ij
        const int idx = tid - 425984;
        const int ij = idx >> 6, b = (idx >> 4) & 3, c = idx & 15;
        const float* Mg = Mm + ij * 1024;
        const float* xb = inp + b * 16384 + c;
        float s = 0.f;
#pragma unroll 8
        for (int pq = 0; pq < 1024; ++pq) s = __builtin_fmaf(Mg[pq], xb[pq * 16], s);
        F[b * 16384 + ij * 16 + c] = s;
        return;
    }
    if (u >= 24) {                            // Gf pack: lane holds G[k=kk*32+quad*8+j][col]
        const int gidx = tid - 98304;         // 0..327679
        const int ijkk = gidx >> 6, l = gidx & 63;
        const int ij = ijkk / 5, kk = ijkk - ij * 5;
        const int quad = l >> 4, col = l & 15;
        const float* Gg = G + ij * 2304;
        float v[8];
#pragma unroll
        for (int j = 0; j < 8; ++j) {
            const int k = kk * 32 + quad * 8 + j;
            v[j] = (k < 144) ? Gg[k * 16 + col] : 0.f;
        }
        uint4 o;
        o.x = pack2(v[0], v[1]); o.y = pack2(v[2], v[3]);
        o.z = pack2(v[4], v[5]); o.w = pack2(v[6], v[7]);
        Gf[ij * 320 + kk * 64 + l] = o;
        return;
    }
    if (u >= 20) {                            // Xf: 16384 float4
        const int idx = tid - 81920;
        const int tile = idx >> 6, ll = idx & 63;
        const int rowb = tile * 16 + (ll >> 4) * 4;
        const int col = ll & 15;
        float4 v;
        v.x = inp[(rowb + 0) * 16 + col];
        v.y = inp[(rowb + 1) * 16 + col];
        v.z = inp[(rowb + 2) * 16 + col];
        v.w = inp[(rowb + 3) * 16 + col];
        Xf[idx] = v;
        return;
    }
    const int row = tid & 4095;
    const int tile = row >> 4, m = row & 15;
    if (u >= 18) {                            // zero-pad k=144..159 (kk=4, quads 2,3)
        const uint4 z = {0, 0, 0, 0};
        A[(tile * 5 + 4) * 64 + (u - 16) * 16 + m] = z;
        return;
    }
    const int tap = u >> 1, h = u & 1;
    const int dh = tap / 3, dw = tap - dh * 3;
    const int b = row >> 10, pq = row & 1023;
    const int p = pq >> 5, q = pq & 31;
    const int pp = p + dh - 1, qq = q + dw - 1;
    const int kk = tap >> 1, quad = (tap & 1) * 2 + h;
    uint4 o = {0, 0, 0, 0};
    if (((unsigned)pp < 32u) && ((unsigned)qq < 32u)) {
        const float4* s4 = (const float4*)(inp + b * 16384 + (pp * 32 + qq) * 16 + 8 * h);
        const float4 f0 = s4[0], f1 = s4[1];
        o.x = pack2(f0.x, f0.y); o.y = pack2(f0.z, f0.w);
        o.z = pack2(f1.x, f1.y); o.w = pack2(f1.z, f1.w);
    }
    A[(tile * 5 + kk) * 64 + quad * 16 + m] = o;
}

// ---------------- Phase 2: 256 blocks x 512 thr, 4 ij per block (R1 structure) --------
__global__ __launch_bounds__(512, 2) void inrf_main(
    const float* __restrict__ Wp,    // (1024 ij, 1024 pq)
    const uint4* __restrict__ Gf,    // bf16 B-frags: [ij*320 + kk*64 + lane]
    const uint4* __restrict__ Aw,    // swizzled bf16 patches, frag (tile,kk) at [..]*64+l
    const f32x4* __restrict__ Xf,    // x in C-frag layout
    const float* __restrict__ F,     // (4,1024,16) = M2@x, fp32 exact
    float* __restrict__ out)         // (4,1024,16)
{
    const int bid = blockIdx.x;      // ij block: handles ij = bid*4 .. bid*4+3
    const int t = threadIdx.x, l = t & 63, w = t >> 6;   // 8 waves
    const int quad = l >> 4;

    __shared__ __align__(16) float W2l[4096];
    __shared__ float red[8][64];

    {   // stage W2 once (16 KB)
        const float4* Wg = (const float4*)(Wp + bid * 4096);
        float4* W4 = (float4*)W2l;
        W4[t] = Wg[t]; W4[t + 512] = Wg[t + 512];
    }

    // B fragments for this block's 4 ij: 20 coalesced dwordx4
    const int ij0 = bid * 4;
    bf16x8 Bf[4][5];
#pragma unroll
    for (int ij = 0; ij < 4; ++ij)
#pragma unroll
        for (int kk = 0; kk < 5; ++kk)
            Bf[ij][kk] = __builtin_bit_cast(bf16x8, Gf[(ij0 + ij) * 320 + kk * 64 + l]);

    __syncthreads();

    const int b = w >> 1;                      // 2 waves per batch element
    const int tile0 = b * 64 + (w & 1) * 32;   // 32 tiles per wave

    f32x4 accv[4];
#pragma unroll
    for (int jj = 0; jj < 4; ++jj) accv[jj] = (f32x4){0.f, 0.f, 0.f, 0.f};

    uint4 A0[5], A1[5];
    f32x4 v0, v1;

    auto prefetch = [&](uint4 (&Ar)[5], f32x4& vr, int tn) {
#pragma unroll
        for (int kk = 0; kk < 5; ++kk) Ar[kk] = Aw[(tn * 5 + kk) * 64 + l];
        vr = Xf[tn * 64 + l];
    };

    const f32x4 zero4 = (f32x4){0.f, 0.f, 0.f, 0.f};

    auto compute = [&](const uint4 (&Ar)[5], const f32x4& vr, int tg) {
        f32x4 C[4];
#pragma unroll
        for (int jj = 0; jj < 4; ++jj) C[jj] = zero4;
#pragma unroll
        for (int kk = 0; kk < 5; ++kk) {
            const bf16x8 a = __builtin_bit_cast(bf16x8, Ar[kk]);
#pragma unroll
            for (int jj = 0; jj < 4; ++jj)
                C[jj] = __builtin_amdgcn_mfma_f32_16x16x32_bf16(a, Bf[jj][kk], C[jj], 0, 0, 0);
        }
        // packed epilogue: acc += w2 * relu(x - S)   (v_pk_add/max/fma_f32)
        const int pqb = (tg & 63) * 16 + quad * 4;
#pragma unroll
        for (int jj = 0; jj < 4; ++jj) {
            const f32x4 w2 = *(const f32x4*)&W2l[jj * 1024 + pqb];
            const f32x4 d = vr - C[jj];
            const f32x4 r = __builtin_elementwise_max(d, zero4);
            accv[jj] += w2 * r;
        }
    };

    prefetch(A0, v0, tile0);
#pragma unroll 1
    for (int i = 0; i < 32; i += 2) {
        prefetch(A1, v1, tile0 + i + 1);
        compute(A0, v0, tile0 + i);
        if (i + 2 < 32) prefetch(A0, v0, tile0 + i + 2);
        compute(A1, v1, tile0 + i + 1);
    }

    // horizontal + quad reduce -> per-wave totals for (ij, col)
#pragma unroll
    for (int jj = 0; jj < 4; ++jj) {
        const f32x4 a = accv[jj];
        float v = (a[0] + a[1]) + (a[2] + a[3]);
        v += __shfl_xor(v, 16);
        v += __shfl_xor(v, 32);
        if (l < 16) red[w][jj * 16 + l] = v;
    }
    __syncthreads();

    if (t < 256) {
        const int ob = t >> 6, oij = (t >> 4) & 3, oc = t & 15;
        const float r0 = red[ob * 2][oij * 16 + oc] + red[ob * 2 + 1][oij * 16 + oc];
        const int o = ob * 16384 + (ij0 + oij) * 16 + oc;
        out[o] = F[o] - r0;    // L = 1
    }
}

extern "C" void kernel_launch(void* const* d_in, const int* in_sizes, int n_in,
                              void* d_out, int out_size, void* d_ws, size_t ws_size,
                              hipStream_t stream) {
    const float* inp = (const float*)d_in[0];   // 65536
    const float* M   = (const float*)d_in[1];   // 1048576
    const float* Wp  = (const float*)d_in[2];   // 1048576
    const float* G   = (const float*)d_in[3];   // 2359296
    float* out = (float*)d_out;

    uint4*  A  = (uint4*)d_ws;                                    // 81920*16B  = 1.31 MB
    float4* Xf = (float4*)((char*)d_ws + 1310720);                // 16384*16B  = 256 KB
    uint4*  Gf = (uint4*)((char*)d_ws + 1572864);                 // 327680*16B = 5.24 MB
    float*  F  = (float*)((char*)d_ws + 6815744);                 // 65536*4B   = 256 KB

    build_pre<<<dim3(1920), dim3(256), 0, stream>>>(inp, M, G, A, Xf, Gf, F);
    inrf_main<<<dim3(256), dim3(512), 0, stream>>>(Wp, Gf, A, (const f32x4*)Xf, F, out);
}

// Round 9
// 116.386 us; speedup vs baseline: 1.0967x; 1.0967x over previous
//
#include <hip/hip_runtime.h>

// INRF fused:  out[b,ij,c] = sum_pq [ M2[ij,pq]*x[b,pq,c] - W2[ij,pq]*relu(x[b,pq,c] - S[b,pq,ij,c]) ]
//   S[b,pq,ij,f] = sum_k patch(x)[b,pq,k] * G[ij,k,f]   (3x3 SAME conv, K=144->pad 160)
//
// Round-9: R8's VALU-cut worked (inrf ~30us, out of top-5) but F=M2@x serialized
//   build_pre to 42us (per-THREAD 1024-deep FMA chain, 65K threads = latency tail).
//   This round: inrf_main byte-identical to R8; F re-parallelized 16x -> one WAVE per
//   (ij,b), lanes = (pq-quad, c), 4 independent 64-deep chains, shfl_xor quad-reduce.
//   R8 inrf structure: R1 ping-pong + (1) M2*x hoisted to F (out = F - sum(W2*relu)),
//   (2) packed-f32 epilogue (v_pk ops), (3) B-frags from pre-packed Gf.

typedef __attribute__((ext_vector_type(8))) short bf16x8;
typedef __attribute__((ext_vector_type(4))) float f32x4;

__device__ inline unsigned short f2bf(float x) {
    unsigned u = __float_as_uint(x);
    u += 0x7FFFu + ((u >> 16) & 1u);          // round-to-nearest-even
    return (unsigned short)(u >> 16);
}
__device__ inline unsigned pack2(float a, float b) {
    return (unsigned)f2bf(a) | ((unsigned)f2bf(b) << 16);
}

// ---------------- Phase 1: A (im2col bf16 frags) + Xf + Gf + F = M2@x ----------------
// unit u = tid>>12:
//   u in [0,18):   A tap = u>>1, h = u&1 -> uint4 at (tile, kk=tap>>1, quad=(tap&1)*2+h, m)
//   u in [18,20):  A zero-pad kk=4, quads 2,3
//   u in [20,24):  Xf C-frag gather, one float4 per (tile, lane)
//   u in [24,104): Gf pack: one uint4 per (ij, kk, lane)
//   u in [104,168): F: one wave per (ij,b); lane=(pq-quad, c); 4 indep chains + reduce
__global__ __launch_bounds__(256) void build_pre(const float* __restrict__ inp,
                                                 const float* __restrict__ Mm,
                                                 const float* __restrict__ G,
                                                 uint4* __restrict__ A,
                                                 float4* __restrict__ Xf,
                                                 uint4* __restrict__ Gf,
                                                 float* __restrict__ F) {
    const int tid = blockIdx.x * 256 + threadIdx.x;
    const int u = tid >> 12;
    if (u >= 104) {                           // F: 4096 waves, one per (ij, b)
        const int fidx = tid - 425984;        // 0..262143
        const int wv = fidx >> 6, l = fidx & 63;
        const int ij = wv >> 2, b = wv & 3;
        const int c = l & 15, qd = l >> 4;    // quad qd covers pq in [qd*256, qd*256+256)
        const float* Mg = Mm + ij * 1024 + qd * 256;
        const float* xb = inp + b * 16384 + qd * 4096 + c;
        float s0 = 0.f, s1 = 0.f, s2 = 0.f, s3 = 0.f;
#pragma unroll 4
        for (int i = 0; i < 256; i += 4) {
            s0 = __builtin_fmaf(Mg[i + 0], xb[(i + 0) * 16], s0);
            s1 = __builtin_fmaf(Mg[i + 1], xb[(i + 1) * 16], s1);
            s2 = __builtin_fmaf(Mg[i + 2], xb[(i + 2) * 16], s2);
            s3 = __builtin_fmaf(Mg[i + 3], xb[(i + 3) * 16], s3);
        }
        float v = (s0 + s1) + (s2 + s3);
        v += __shfl_xor(v, 16);               // fold pq-quads
        v += __shfl_xor(v, 32);
        if (l < 16) F[b * 16384 + ij * 16 + c] = v;
        return;
    }
    if (u >= 24) {                            // Gf pack: lane holds G[k=kk*32+quad*8+j][col]
        const int gidx = tid - 98304;         // 0..327679
        const int ijkk = gidx >> 6, l = gidx & 63;
        const int ij = ijkk / 5, kk = ijkk - ij * 5;
        const int quad = l >> 4, col = l & 15;
        const float* Gg = G + ij * 2304;
        float v[8];
#pragma unroll
        for (int j = 0; j < 8; ++j) {
            const int k = kk * 32 + quad * 8 + j;
            v[j] = (k < 144) ? Gg[k * 16 + col] : 0.f;
        }
        uint4 o;
        o.x = pack2(v[0], v[1]); o.y = pack2(v[2], v[3]);
        o.z = pack2(v[4], v[5]); o.w = pack2(v[6], v[7]);
        Gf[ij * 320 + kk * 64 + l] = o;
        return;
    }
    if (u >= 20) {                            // Xf: 16384 float4
        const int idx = tid - 81920;
        const int tile = idx >> 6, ll = idx & 63;
        const int rowb = tile * 16 + (ll >> 4) * 4;
        const int col = ll & 15;
        float4 v;
        v.x = inp[(rowb + 0) * 16 + col];
        v.y = inp[(rowb + 1) * 16 + col];
        v.z = inp[(rowb + 2) * 16 + col];
        v.w = inp[(rowb + 3) * 16 + col];
        Xf[idx] = v;
        return;
    }
    const int row = tid & 4095;
    const int tile = row >> 4, m = row & 15;
    if (u >= 18) {                            // zero-pad k=144..159 (kk=4, quads 2,3)
        const uint4 z = {0, 0, 0, 0};
        A[(tile * 5 + 4) * 64 + (u - 16) * 16 + m] = z;
        return;
    }
    const int tap = u >> 1, h = u & 1;
    const int dh = tap / 3, dw = tap - dh * 3;
    const int b = row >> 10, pq = row & 1023;
    const int p = pq >> 5, q = pq & 31;
    const int pp = p + dh - 1, qq = q + dw - 1;
    const int kk = tap >> 1, quad = (tap & 1) * 2 + h;
    uint4 o = {0, 0, 0, 0};
    if (((unsigned)pp < 32u) && ((unsigned)qq < 32u)) {
        const float4* s4 = (const float4*)(inp + b * 16384 + (pp * 32 + qq) * 16 + 8 * h);
        const float4 f0 = s4[0], f1 = s4[1];
        o.x = pack2(f0.x, f0.y); o.y = pack2(f0.z, f0.w);
        o.z = pack2(f1.x, f1.y); o.w = pack2(f1.z, f1.w);
    }
    A[(tile * 5 + kk) * 64 + quad * 16 + m] = o;
}

// ---------------- Phase 2: 256 blocks x 512 thr, 4 ij per block (R8 structure) --------
__global__ __launch_bounds__(512, 2) void inrf_main(
    const float* __restrict__ Wp,    // (1024 ij, 1024 pq)
    const uint4* __restrict__ Gf,    // bf16 B-frags: [ij*320 + kk*64 + lane]
    const uint4* __restrict__ Aw,    // swizzled bf16 patches, frag (tile,kk) at [..]*64+l
    const f32x4* __restrict__ Xf,    // x in C-frag layout
    const float* __restrict__ F,     // (4,1024,16) = M2@x, fp32 exact
    float* __restrict__ out)         // (4,1024,16)
{
    const int bid = blockIdx.x;      // ij block: handles ij = bid*4 .. bid*4+3
    const int t = threadIdx.x, l = t & 63, w = t >> 6;   // 8 waves
    const int quad = l >> 4;

    __shared__ __align__(16) float W2l[4096];
    __shared__ float red[8][64];

    {   // stage W2 once (16 KB)
        const float4* Wg = (const float4*)(Wp + bid * 4096);
        float4* W4 = (float4*)W2l;
        W4[t] = Wg[t]; W4[t + 512] = Wg[t + 512];
    }

    // B fragments for this block's 4 ij: 20 coalesced dwordx4
    const int ij0 = bid * 4;
    bf16x8 Bf[4][5];
#pragma unroll
    for (int ij = 0; ij < 4; ++ij)
#pragma unroll
        for (int kk = 0; kk < 5; ++kk)
            Bf[ij][kk] = __builtin_bit_cast(bf16x8, Gf[(ij0 + ij) * 320 + kk * 64 + l]);

    __syncthreads();

    const int b = w >> 1;                      // 2 waves per batch element
    const int tile0 = b * 64 + (w & 1) * 32;   // 32 tiles per wave

    f32x4 accv[4];
#pragma unroll
    for (int jj = 0; jj < 4; ++jj) accv[jj] = (f32x4){0.f, 0.f, 0.f, 0.f};

    uint4 A0[5], A1[5];
    f32x4 v0, v1;

    auto prefetch = [&](uint4 (&Ar)[5], f32x4& vr, int tn) {
#pragma unroll
        for (int kk = 0; kk < 5; ++kk) Ar[kk] = Aw[(tn * 5 + kk) * 64 + l];
        vr = Xf[tn * 64 + l];
    };

    const f32x4 zero4 = (f32x4){0.f, 0.f, 0.f, 0.f};

    auto compute = [&](const uint4 (&Ar)[5], const f32x4& vr, int tg) {
        f32x4 C[4];
#pragma unroll
        for (int jj = 0; jj < 4; ++jj) C[jj] = zero4;
#pragma unroll
        for (int kk = 0; kk < 5; ++kk) {
            const bf16x8 a = __builtin_bit_cast(bf16x8, Ar[kk]);
#pragma unroll
            for (int jj = 0; jj < 4; ++jj)
                C[jj] = __builtin_amdgcn_mfma_f32_16x16x32_bf16(a, Bf[jj][kk], C[jj], 0, 0, 0);
        }
        // packed epilogue: acc += w2 * relu(x - S)   (v_pk_add/max/fma_f32)
        const int pqb = (tg & 63) * 16 + quad * 4;
#pragma unroll
        for (int jj = 0; jj < 4; ++jj) {
            const f32x4 w2 = *(const f32x4*)&W2l[jj * 1024 + pqb];
            const f32x4 d = vr - C[jj];
            const f32x4 r = __builtin_elementwise_max(d, zero4);
            accv[jj] += w2 * r;
        }
    };

    prefetch(A0, v0, tile0);
#pragma unroll 1
    for (int i = 0; i < 32; i += 2) {
        prefetch(A1, v1, tile0 + i + 1);
        compute(A0, v0, tile0 + i);
        if (i + 2 < 32) prefetch(A0, v0, tile0 + i + 2);
        compute(A1, v1, tile0 + i + 1);
    }

    // horizontal + quad reduce -> per-wave totals for (ij, col)
#pragma unroll
    for (int jj = 0; jj < 4; ++jj) {
        const f32x4 a = accv[jj];
        float v = (a[0] + a[1]) + (a[2] + a[3]);
        v += __shfl_xor(v, 16);
        v += __shfl_xor(v, 32);
        if (l < 16) red[w][jj * 16 + l] = v;
    }
    __syncthreads();

    if (t < 256) {
        const int ob = t >> 6, oij = (t >> 4) & 3, oc = t & 15;
        const float r0 = red[ob * 2][oij * 16 + oc] + red[ob * 2 + 1][oij * 16 + oc];
        const int o = ob * 16384 + (ij0 + oij) * 16 + oc;
        out[o] = F[o] - r0;    // L = 1
    }
}

extern "C" void kernel_launch(void* const* d_in, const int* in_sizes, int n_in,
                              void* d_out, int out_size, void* d_ws, size_t ws_size,
                              hipStream_t stream) {
    const float* inp = (const float*)d_in[0];   // 65536
    const float* M   = (const float*)d_in[1];   // 1048576
    const float* Wp  = (const float*)d_in[2];   // 1048576
    const float* G   = (const float*)d_in[3];   // 2359296
    float* out = (float*)d_out;

    uint4*  A  = (uint4*)d_ws;                                    // 81920*16B  = 1.31 MB
    float4* Xf = (float4*)((char*)d_ws + 1310720);                // 16384*16B  = 256 KB
    uint4*  Gf = (uint4*)((char*)d_ws + 1572864);                 // 327680*16B = 5.24 MB
    float*  F  = (float*)((char*)d_ws + 6815744);                 // 65536*4B   = 256 KB

    build_pre<<<dim3(2688), dim3(256), 0, stream>>>(inp, M, G, A, Xf, Gf, F);
    inrf_main<<<dim3(256), dim3(512), 0, stream>>>(Wp, Gf, A, (const f32x4*)Xf, F, out);
}